// Round 1
// baseline (762.878 us; speedup 1.0000x reference)
//
#include <hip/hip_runtime.h>

#define N_NODES  50000
#define N_EDGES  800000
#define HIDDEN   128
#define N_GRAPHS 256
#define N_CLASSES 10
#define AS_LD    132   // padded A-tile leading dim (floats): +4 keeps 16B align, breaks bank aliasing

// ---------------- CSR build ----------------
__global__ void deg_kernel(const int* __restrict__ dst, int* __restrict__ deg) {
    int e = blockIdx.x * blockDim.x + threadIdx.x;
    if (e < N_EDGES) atomicAdd(&deg[dst[e]], 1);
}

// Disjoint row ranges via wave-aggregated atomic on a global counter.
// Ranges need not be in node order (sum is order-free).
__global__ void offsets_kernel(const int* __restrict__ deg, int* __restrict__ row_start,
                               int* __restrict__ counter) {
    int n = blockIdx.x * blockDim.x + threadIdx.x;
    int d = (n < N_NODES) ? deg[n] : 0;
    int lane = threadIdx.x & 63;
    // inclusive wave scan
    int incl = d;
    #pragma unroll
    for (int off = 1; off < 64; off <<= 1) {
        int v = __shfl_up(incl, off, 64);
        if (lane >= off) incl += v;
    }
    int excl = incl - d;
    int total = __shfl(incl, 63, 64);
    int base = 0;
    if (lane == 0) base = atomicAdd(counter, total);
    base = __shfl(base, 0, 64);
    if (n < N_NODES) row_start[n] = base + excl;
}

__global__ void fill_kernel(const int* __restrict__ src, const int* __restrict__ dst,
                            const int* __restrict__ row_start, int* __restrict__ cursor,
                            int* __restrict__ csr_src) {
    int e = blockIdx.x * blockDim.x + threadIdx.x;
    if (e >= N_EDGES) return;
    int d = dst[e];
    int pos = row_start[d] + atomicAdd(&cursor[d], 1);
    csr_src[pos] = src[e];
}

// ---------------- aggregation: T[n] = X[n] + sum_{e: dst==n} X[src[e]] ----------------
// one 32-lane group per node; lane = float4 chunk (32 * 16B = 512B row)
__global__ void agg_kernel(const float4* __restrict__ X, const int* __restrict__ row_start,
                           const int* __restrict__ deg, const int* __restrict__ csr_src,
                           float4* __restrict__ T) {
    int gid = blockIdx.x * blockDim.x + threadIdx.x;
    int n = gid >> 5;
    int c = gid & 31;
    if (n >= N_NODES) return;
    float4 acc = X[(size_t)n * 32 + c];   // self term (fuses x + agg)
    int rs = row_start[n];
    int d  = deg[n];
    for (int i = 0; i < d; ++i) {
        int s = csr_src[rs + i];
        float4 v = X[(size_t)s * 32 + c];
        acc.x += v.x; acc.y += v.y; acc.z += v.z; acc.w += v.w;
    }
    T[(size_t)n * 32 + c] = acc;
}

// ---------------- fp32 tiled matmul: C = [relu](A @ W + b), A: N x 128, W: 128 x 128 ----------------
__global__ __launch_bounds__(256, 1)
void mm_kernel(const float* __restrict__ A, const float* __restrict__ W,
               const float* __restrict__ bias, float* __restrict__ C, int relu) {
    __shared__ __align__(16) float Ws[HIDDEN * HIDDEN];   // 64 KB
    __shared__ __align__(16) float As[64 * AS_LD];        // ~33 KB
    __shared__ __align__(16) float bs[HIDDEN];

    int t = threadIdx.x;
    {   // load W: 16384 floats = 4096 float4, 16 per thread
        const float4* W4 = (const float4*)W;
        float4* Ws4 = (float4*)Ws;
        #pragma unroll
        for (int i = 0; i < 16; ++i) Ws4[i * 256 + t] = W4[i * 256 + t];
    }
    if (t < 32) ((float4*)bs)[t] = ((const float4*)bias)[t];

    const int ntiles = (N_NODES + 63) / 64;
    int tx = t & 15, ty = t >> 4;        // tx: col group (8 cols), ty: row group (4 rows)
    int tx8 = tx * 8, ty4 = ty * 4;

    for (int tile = blockIdx.x; tile < ntiles; tile += gridDim.x) {
        __syncthreads();   // previous-iter readers done (also orders first-iter W load)
        {   // load A tile: 64 rows x 128 = 2048 float4, 8 per thread
            const float4* A4 = (const float4*)A;
            float4* As4 = (float4*)As;
            #pragma unroll
            for (int i = 0; i < 8; ++i) {
                int idx = i * 256 + t;          // 0..2047
                int row = idx >> 5, c4 = idx & 31;
                int gr = tile * 64 + row;
                float4 v = make_float4(0.f, 0.f, 0.f, 0.f);
                if (gr < N_NODES) v = A4[(size_t)gr * 32 + c4];
                As4[row * (AS_LD / 4) + c4] = v;
            }
        }
        __syncthreads();

        float acc[4][8];
        #pragma unroll
        for (int r = 0; r < 4; ++r)
            #pragma unroll
            for (int c = 0; c < 8; ++c) acc[r][c] = 0.f;

        #pragma unroll 4
        for (int k = 0; k < HIDDEN; ++k) {
            float a0 = As[(ty4 + 0) * AS_LD + k];
            float a1 = As[(ty4 + 1) * AS_LD + k];
            float a2 = As[(ty4 + 2) * AS_LD + k];
            float a3 = As[(ty4 + 3) * AS_LD + k];
            float4 w0 = *(const float4*)(Ws + k * HIDDEN + tx8);
            float4 w1 = *(const float4*)(Ws + k * HIDDEN + tx8 + 4);
            float wv[8] = {w0.x, w0.y, w0.z, w0.w, w1.x, w1.y, w1.z, w1.w};
            float av[4] = {a0, a1, a2, a3};
            #pragma unroll
            for (int r = 0; r < 4; ++r)
                #pragma unroll
                for (int c = 0; c < 8; ++c) acc[r][c] = fmaf(av[r], wv[c], acc[r][c]);
        }

        #pragma unroll
        for (int r = 0; r < 4; ++r) {
            int gr = tile * 64 + ty4 + r;
            if (gr < N_NODES) {
                float o[8];
                #pragma unroll
                for (int c = 0; c < 8; ++c) {
                    o[c] = acc[r][c] + bs[tx8 + c];
                    if (relu) o[c] = fmaxf(o[c], 0.f);
                }
                float4* Crow = (float4*)(C + (size_t)gr * HIDDEN);
                Crow[tx * 2 + 0] = make_float4(o[0], o[1], o[2], o[3]);
                Crow[tx * 2 + 1] = make_float4(o[4], o[5], o[6], o[7]);
            }
        }
    }
}

// ---------------- pooling ----------------
// batch is sorted: run-length accumulate 8 nodes per thread before atomics
__global__ void pool_accum(const float4* __restrict__ H, const int* __restrict__ batch,
                           float* __restrict__ pooled) {
    int gid = blockIdx.x * blockDim.x + threadIdx.x;
    int c  = gid & 31;
    int nb = gid >> 5;
    int n0 = nb * 8;
    if (n0 >= N_NODES) return;
    int gcur = -1;
    float4 acc = make_float4(0.f, 0.f, 0.f, 0.f);
    for (int i = 0; i < 8; ++i) {
        int n = n0 + i;
        if (n >= N_NODES) break;
        int g = batch[n];
        if (g != gcur) {
            if (gcur >= 0) {
                float* p = pooled + (size_t)gcur * HIDDEN + c * 4;
                atomicAdd(p + 0, acc.x); atomicAdd(p + 1, acc.y);
                atomicAdd(p + 2, acc.z); atomicAdd(p + 3, acc.w);
            }
            acc = make_float4(0.f, 0.f, 0.f, 0.f);
            gcur = g;
        }
        float4 v = H[(size_t)n * 32 + c];
        acc.x += v.x; acc.y += v.y; acc.z += v.z; acc.w += v.w;
    }
    if (gcur >= 0) {
        float* p = pooled + (size_t)gcur * HIDDEN + c * 4;
        atomicAdd(p + 0, acc.x); atomicAdd(p + 1, acc.y);
        atomicAdd(p + 2, acc.z); atomicAdd(p + 3, acc.w);
    }
}

__global__ void count_kernel(const int* __restrict__ batch, float* __restrict__ cnt) {
    int n = blockIdx.x * blockDim.x + threadIdx.x;
    if (n < N_NODES) atomicAdd(&cnt[batch[n]], 1.0f);
}

__global__ void head_kernel(const float* __restrict__ pooled, const float* __restrict__ cnt,
                            const float* __restrict__ Wl, const float* __restrict__ bl,
                            float* __restrict__ out) {
    int g = blockIdx.x;
    int t = threadIdx.x;   // 128 threads
    __shared__ float p[HIDDEN];
    float inv = 1.0f / fmaxf(cnt[g], 1.0f);
    p[t] = pooled[(size_t)g * HIDDEN + t] * inv;
    __syncthreads();
    if (t < N_CLASSES) {
        float s = bl[t];
        for (int k = 0; k < HIDDEN; ++k) s = fmaf(p[k], Wl[k * N_CLASSES + t], s);
        out[(size_t)g * N_CLASSES + t] = s;
    }
}

extern "C" void kernel_launch(void* const* d_in, const int* in_sizes, int n_in,
                              void* d_out, int out_size, void* d_ws, size_t ws_size,
                              hipStream_t stream) {
    const float* x   = (const float*)d_in[0];
    const int*   ei  = (const int*)d_in[1];       // [2][N_EDGES]: row0=src, row1=dst
    const int*   bat = (const int*)d_in[2];
    const float* W1  = (const float*)d_in[3];
    const float* b1  = (const float*)d_in[4];
    const float* W2  = (const float*)d_in[5];
    const float* b2  = (const float*)d_in[6];
    const float* Wl  = (const float*)d_in[7];
    const float* bl  = (const float*)d_in[8];
    float* out = (float*)d_out;

    const int* src = ei;
    const int* dst = ei + N_EDGES;

    // workspace layout (256B aligned chunks)
    char* w = (char*)d_ws;
    size_t off = 0;
    auto alloc = [&](size_t bytes) { void* p = w + off; off = (off + bytes + 255) & ~(size_t)255; return p; };
    float* t_buf   = (float*)alloc((size_t)N_NODES * HIDDEN * 4);
    float* z_buf   = (float*)alloc((size_t)N_NODES * HIDDEN * 4);
    float* h_buf   = (float*)alloc((size_t)N_NODES * HIDDEN * 4);
    int*   deg     = (int*)  alloc((size_t)N_NODES * 4);
    int*   rowst   = (int*)  alloc((size_t)N_NODES * 4);
    int*   cursor  = (int*)  alloc((size_t)N_NODES * 4);
    int*   csr_src = (int*)  alloc((size_t)N_EDGES * 4);
    int*   counter = (int*)  alloc(256);
    float* pooled  = (float*)alloc((size_t)N_GRAPHS * HIDDEN * 4);
    float* cnt     = (float*)alloc((size_t)N_GRAPHS * 4);
    (void)ws_size; (void)in_sizes; (void)n_in; (void)out_size;

    hipMemsetAsync(deg,     0, (size_t)N_NODES * 4, stream);
    hipMemsetAsync(cursor,  0, (size_t)N_NODES * 4, stream);
    hipMemsetAsync(counter, 0, 256, stream);
    hipMemsetAsync(pooled,  0, (size_t)N_GRAPHS * HIDDEN * 4, stream);
    hipMemsetAsync(cnt,     0, (size_t)N_GRAPHS * 4, stream);

    // CSR build (once; reused by all 3 layers)
    deg_kernel<<<(N_EDGES + 255) / 256, 256, 0, stream>>>(dst, deg);
    offsets_kernel<<<(N_NODES + 255) / 256, 256, 0, stream>>>(deg, rowst, counter);
    fill_kernel<<<(N_EDGES + 255) / 256, 256, 0, stream>>>(src, dst, rowst, cursor, csr_src);

    const int agg_grid = (N_NODES * 32 + 255) / 256;
    const int mm_grid  = (N_NODES + 63) / 64;

    // layer 1 (input x)
    agg_kernel<<<agg_grid, 256, 0, stream>>>((const float4*)x, rowst, deg, csr_src, (float4*)t_buf);
    mm_kernel<<<mm_grid, 256, 0, stream>>>(t_buf, W1, b1, z_buf, 1);
    mm_kernel<<<mm_grid, 256, 0, stream>>>(z_buf, W2, b2, h_buf, 1);
    // layer 2
    agg_kernel<<<agg_grid, 256, 0, stream>>>((const float4*)h_buf, rowst, deg, csr_src, (float4*)t_buf);
    mm_kernel<<<mm_grid, 256, 0, stream>>>(t_buf, W1, b1, z_buf, 1);
    mm_kernel<<<mm_grid, 256, 0, stream>>>(z_buf, W2, b2, h_buf, 1);
    // layer 3 (no outer relu)
    agg_kernel<<<agg_grid, 256, 0, stream>>>((const float4*)h_buf, rowst, deg, csr_src, (float4*)t_buf);
    mm_kernel<<<mm_grid, 256, 0, stream>>>(t_buf, W1, b1, z_buf, 1);
    mm_kernel<<<mm_grid, 256, 0, stream>>>(z_buf, W2, b2, h_buf, 0);

    // mean pool + head
    const int pa_grid = ((N_NODES + 7) / 8 * 32 + 255) / 256;
    pool_accum<<<pa_grid, 256, 0, stream>>>((const float4*)h_buf, bat, pooled);
    count_kernel<<<(N_NODES + 255) / 256, 256, 0, stream>>>(bat, cnt);
    head_kernel<<<N_GRAPHS, HIDDEN, 0, stream>>>(pooled, cnt, Wl, bl, out);
}

// Round 2
// 672.302 us; speedup vs baseline: 1.1347x; 1.1347x over previous
//
#include <hip/hip_runtime.h>

#define N_NODES  50000
#define N_EDGES  800000
#define HIDDEN   128
#define N_GRAPHS 256
#define N_CLASSES 10
#define AS_LD    132   // padded A-tile leading dim (floats): +4 keeps 16B align, breaks bank aliasing

// ---------------- CSR build ----------------
__global__ void deg_kernel(const int* __restrict__ dst, int* __restrict__ deg) {
    int e = blockIdx.x * blockDim.x + threadIdx.x;
    if (e < N_EDGES) atomicAdd(&deg[dst[e]], 1);
}

// Disjoint row ranges via wave-aggregated atomic on a global counter.
// Ranges need not be in node order (sum is order-free).
__global__ void offsets_kernel(const int* __restrict__ deg, int* __restrict__ row_start,
                               int* __restrict__ counter) {
    int n = blockIdx.x * blockDim.x + threadIdx.x;
    int d = (n < N_NODES) ? deg[n] : 0;
    int lane = threadIdx.x & 63;
    // inclusive wave scan
    int incl = d;
    #pragma unroll
    for (int off = 1; off < 64; off <<= 1) {
        int v = __shfl_up(incl, off, 64);
        if (lane >= off) incl += v;
    }
    int excl = incl - d;
    int total = __shfl(incl, 63, 64);
    int base = 0;
    if (lane == 0) base = atomicAdd(counter, total);
    base = __shfl(base, 0, 64);
    if (n < N_NODES) row_start[n] = base + excl;
}

__global__ void fill_kernel(const int* __restrict__ src, const int* __restrict__ dst,
                            const int* __restrict__ row_start, int* __restrict__ cursor,
                            int* __restrict__ csr_src) {
    int e = blockIdx.x * blockDim.x + threadIdx.x;
    if (e >= N_EDGES) return;
    int d = dst[e];
    int pos = row_start[d] + atomicAdd(&cursor[d], 1);
    csr_src[pos] = src[e];
}

// ---------------- aggregation: T[n] = X[n] + sum_{e: dst==n} X[src[e]] ----------------
// one 32-lane group per node; lane = float4 chunk (32 * 16B = 512B row)
__global__ void agg_kernel(const float4* __restrict__ X, const int* __restrict__ row_start,
                           const int* __restrict__ deg, const int* __restrict__ csr_src,
                           float4* __restrict__ T) {
    int gid = blockIdx.x * blockDim.x + threadIdx.x;
    int n = gid >> 5;
    int c = gid & 31;
    if (n >= N_NODES) return;
    float4 acc = X[(size_t)n * 32 + c];   // self term (fuses x + agg)
    int rs = row_start[n];
    int d  = deg[n];
    int i = 0;
    // 4-wide manual unroll: 4 independent idx->row load chains in flight
    for (; i + 4 <= d; i += 4) {
        int s0 = csr_src[rs + i + 0];
        int s1 = csr_src[rs + i + 1];
        int s2 = csr_src[rs + i + 2];
        int s3 = csr_src[rs + i + 3];
        float4 v0 = X[(size_t)s0 * 32 + c];
        float4 v1 = X[(size_t)s1 * 32 + c];
        float4 v2 = X[(size_t)s2 * 32 + c];
        float4 v3 = X[(size_t)s3 * 32 + c];
        acc.x += v0.x + v1.x + v2.x + v3.x;
        acc.y += v0.y + v1.y + v2.y + v3.y;
        acc.z += v0.z + v1.z + v2.z + v3.z;
        acc.w += v0.w + v1.w + v2.w + v3.w;
    }
    for (; i < d; ++i) {
        int s = csr_src[rs + i];
        float4 v = X[(size_t)s * 32 + c];
        acc.x += v.x; acc.y += v.y; acc.z += v.z; acc.w += v.w;
    }
    T[(size_t)n * 32 + c] = acc;
}

// ---------------- fp32 tiled matmul: C = [relu](A @ W + b), A: N x 128, W: 128 x 128 ----------------
__global__ __launch_bounds__(256, 1)
void mm_kernel(const float* __restrict__ A, const float* __restrict__ W,
               const float* __restrict__ bias, float* __restrict__ C, int relu) {
    __shared__ __align__(16) float Ws[HIDDEN * HIDDEN];   // 64 KB
    __shared__ __align__(16) float As[64 * AS_LD];        // ~33 KB
    __shared__ __align__(16) float bs[HIDDEN];

    int t = threadIdx.x;
    {   // load W: 16384 floats = 4096 float4, 16 per thread
        const float4* W4 = (const float4*)W;
        float4* Ws4 = (float4*)Ws;
        #pragma unroll
        for (int i = 0; i < 16; ++i) Ws4[i * 256 + t] = W4[i * 256 + t];
    }
    if (t < 32) ((float4*)bs)[t] = ((const float4*)bias)[t];

    const int ntiles = (N_NODES + 63) / 64;
    int tx = t & 15, ty = t >> 4;        // tx: col group (8 cols), ty: row group (4 rows)
    int tx8 = tx * 8, ty4 = ty * 4;

    for (int tile = blockIdx.x; tile < ntiles; tile += gridDim.x) {
        __syncthreads();   // previous-iter readers done (also orders first-iter W load)
        {   // load A tile: 64 rows x 128 = 2048 float4, 8 per thread
            const float4* A4 = (const float4*)A;
            float4* As4 = (float4*)As;
            #pragma unroll
            for (int i = 0; i < 8; ++i) {
                int idx = i * 256 + t;          // 0..2047
                int row = idx >> 5, c4 = idx & 31;
                int gr = tile * 64 + row;
                float4 v = make_float4(0.f, 0.f, 0.f, 0.f);
                if (gr < N_NODES) v = A4[(size_t)gr * 32 + c4];
                As4[row * (AS_LD / 4) + c4] = v;
            }
        }
        __syncthreads();

        float acc[4][8];
        #pragma unroll
        for (int r = 0; r < 4; ++r)
            #pragma unroll
            for (int c = 0; c < 8; ++c) acc[r][c] = 0.f;

        #pragma unroll 4
        for (int k = 0; k < HIDDEN; ++k) {
            float a0 = As[(ty4 + 0) * AS_LD + k];
            float a1 = As[(ty4 + 1) * AS_LD + k];
            float a2 = As[(ty4 + 2) * AS_LD + k];
            float a3 = As[(ty4 + 3) * AS_LD + k];
            float4 w0 = *(const float4*)(Ws + k * HIDDEN + tx8);
            float4 w1 = *(const float4*)(Ws + k * HIDDEN + tx8 + 4);
            float wv[8] = {w0.x, w0.y, w0.z, w0.w, w1.x, w1.y, w1.z, w1.w};
            float av[4] = {a0, a1, a2, a3};
            #pragma unroll
            for (int r = 0; r < 4; ++r)
                #pragma unroll
                for (int c = 0; c < 8; ++c) acc[r][c] = fmaf(av[r], wv[c], acc[r][c]);
        }

        #pragma unroll
        for (int r = 0; r < 4; ++r) {
            int gr = tile * 64 + ty4 + r;
            if (gr < N_NODES) {
                float o[8];
                #pragma unroll
                for (int c = 0; c < 8; ++c) {
                    o[c] = acc[r][c] + bs[tx8 + c];
                    if (relu) o[c] = fmaxf(o[c], 0.f);
                }
                float4* Crow = (float4*)(C + (size_t)gr * HIDDEN);
                Crow[tx * 2 + 0] = make_float4(o[0], o[1], o[2], o[3]);
                Crow[tx * 2 + 1] = make_float4(o[4], o[5], o[6], o[7]);
            }
        }
    }
}

// ---------------- fused pool + mean + linear head ----------------
// batch is sorted: one block per graph; binary-search row range, segmented sum
// (coalesced, zero atomics), mean, then 128x10 head in-block.
__global__ void pool_head_kernel(const float* __restrict__ H, const int* __restrict__ batch,
                                 const float* __restrict__ Wl, const float* __restrict__ bl,
                                 float* __restrict__ out) {
    int g = blockIdx.x;
    int t = threadIdx.x;   // 256 threads
    __shared__ int bounds[2];
    __shared__ float acc2[2 * HIDDEN];
    __shared__ float mean[HIDDEN];

    if (t < 2) {
        int target = g + t;
        int lo = 0, hi = N_NODES;          // lower_bound(batch, target)
        while (lo < hi) {
            int mid = (lo + hi) >> 1;
            if (batch[mid] < target) lo = mid + 1; else hi = mid;
        }
        bounds[t] = lo;
    }
    __syncthreads();
    int r0 = bounds[0], r1 = bounds[1];

    int c = t & 127, half = t >> 7;        // 2 rows in flight, 128 coalesced cols each
    float s = 0.f;
    for (int r = r0 + half; r < r1; r += 2)
        s += H[(size_t)r * HIDDEN + c];
    acc2[half * HIDDEN + c] = s;
    __syncthreads();
    if (t < HIDDEN) {
        float cntf = (float)(r1 - r0);
        mean[t] = (acc2[t] + acc2[HIDDEN + t]) / fmaxf(cntf, 1.0f);
    }
    __syncthreads();
    if (t < N_CLASSES) {
        float o = bl[t];
        #pragma unroll 8
        for (int k = 0; k < HIDDEN; ++k) o = fmaf(mean[k], Wl[k * N_CLASSES + t], o);
        out[(size_t)g * N_CLASSES + t] = o;
    }
}

extern "C" void kernel_launch(void* const* d_in, const int* in_sizes, int n_in,
                              void* d_out, int out_size, void* d_ws, size_t ws_size,
                              hipStream_t stream) {
    const float* x   = (const float*)d_in[0];
    const int*   ei  = (const int*)d_in[1];       // [2][N_EDGES]: row0=src, row1=dst
    const int*   bat = (const int*)d_in[2];
    const float* W1  = (const float*)d_in[3];
    const float* b1  = (const float*)d_in[4];
    const float* W2  = (const float*)d_in[5];
    const float* b2  = (const float*)d_in[6];
    const float* Wl  = (const float*)d_in[7];
    const float* bl  = (const float*)d_in[8];
    float* out = (float*)d_out;

    const int* src = ei;
    const int* dst = ei + N_EDGES;

    // workspace layout (256B aligned chunks)
    char* w = (char*)d_ws;
    size_t off = 0;
    auto alloc = [&](size_t bytes) { void* p = w + off; off = (off + bytes + 255) & ~(size_t)255; return p; };
    float* t_buf   = (float*)alloc((size_t)N_NODES * HIDDEN * 4);
    float* z_buf   = (float*)alloc((size_t)N_NODES * HIDDEN * 4);
    float* h_buf   = (float*)alloc((size_t)N_NODES * HIDDEN * 4);
    int*   deg     = (int*)  alloc((size_t)N_NODES * 4);
    int*   rowst   = (int*)  alloc((size_t)N_NODES * 4);
    int*   cursor  = (int*)  alloc((size_t)N_NODES * 4);
    int*   csr_src = (int*)  alloc((size_t)N_EDGES * 4);
    int*   counter = (int*)  alloc(256);
    (void)ws_size; (void)in_sizes; (void)n_in; (void)out_size;

    hipMemsetAsync(deg,     0, (size_t)N_NODES * 4, stream);
    hipMemsetAsync(cursor,  0, (size_t)N_NODES * 4, stream);
    hipMemsetAsync(counter, 0, 256, stream);

    // CSR build (once; reused by all 3 layers)
    deg_kernel<<<(N_EDGES + 255) / 256, 256, 0, stream>>>(dst, deg);
    offsets_kernel<<<(N_NODES + 255) / 256, 256, 0, stream>>>(deg, rowst, counter);
    fill_kernel<<<(N_EDGES + 255) / 256, 256, 0, stream>>>(src, dst, rowst, cursor, csr_src);

    const int agg_grid = (N_NODES * 32 + 255) / 256;
    const int mm_grid  = (N_NODES + 63) / 64;

    // layer 1 (input x)
    agg_kernel<<<agg_grid, 256, 0, stream>>>((const float4*)x, rowst, deg, csr_src, (float4*)t_buf);
    mm_kernel<<<mm_grid, 256, 0, stream>>>(t_buf, W1, b1, z_buf, 1);
    mm_kernel<<<mm_grid, 256, 0, stream>>>(z_buf, W2, b2, h_buf, 1);
    // layer 2
    agg_kernel<<<agg_grid, 256, 0, stream>>>((const float4*)h_buf, rowst, deg, csr_src, (float4*)t_buf);
    mm_kernel<<<mm_grid, 256, 0, stream>>>(t_buf, W1, b1, z_buf, 1);
    mm_kernel<<<mm_grid, 256, 0, stream>>>(z_buf, W2, b2, h_buf, 1);
    // layer 3 (no outer relu)
    agg_kernel<<<agg_grid, 256, 0, stream>>>((const float4*)h_buf, rowst, deg, csr_src, (float4*)t_buf);
    mm_kernel<<<mm_grid, 256, 0, stream>>>(t_buf, W1, b1, z_buf, 1);
    mm_kernel<<<mm_grid, 256, 0, stream>>>(z_buf, W2, b2, h_buf, 0);

    // fused mean-pool + head (batch sorted -> binary-search boundaries, no atomics)
    pool_head_kernel<<<N_GRAPHS, 256, 0, stream>>>(h_buf, bat, Wl, bl, out);
}

// Round 3
// 558.439 us; speedup vs baseline: 1.3661x; 1.2039x over previous
//
#include <hip/hip_runtime.h>

#define N_NODES  50000
#define N_EDGES  800000
#define HIDDEN   128
#define N_GRAPHS 256
#define N_CLASSES 10

typedef short short8 __attribute__((ext_vector_type(8)));
typedef float floatx4 __attribute__((ext_vector_type(4)));

// ---------------- CSR build ----------------
__global__ void deg_kernel(const int* __restrict__ dst, int* __restrict__ deg) {
    int e = blockIdx.x * blockDim.x + threadIdx.x;
    if (e < N_EDGES) atomicAdd(&deg[dst[e]], 1);
}

__global__ void offsets_kernel(const int* __restrict__ deg, int* __restrict__ row_start,
                               int* __restrict__ counter) {
    int n = blockIdx.x * blockDim.x + threadIdx.x;
    int d = (n < N_NODES) ? deg[n] : 0;
    int lane = threadIdx.x & 63;
    int incl = d;
    #pragma unroll
    for (int off = 1; off < 64; off <<= 1) {
        int v = __shfl_up(incl, off, 64);
        if (lane >= off) incl += v;
    }
    int excl = incl - d;
    int total = __shfl(incl, 63, 64);
    int base = 0;
    if (lane == 0) base = atomicAdd(counter, total);
    base = __shfl(base, 0, 64);
    if (n < N_NODES) row_start[n] = base + excl;
}

__global__ void fill_kernel(const int* __restrict__ src, const int* __restrict__ dst,
                            const int* __restrict__ row_start, int* __restrict__ cursor,
                            int* __restrict__ csr_src) {
    int e = blockIdx.x * blockDim.x + threadIdx.x;
    if (e >= N_EDGES) return;
    int d = dst[e];
    int pos = row_start[d] + atomicAdd(&cursor[d], 1);
    csr_src[pos] = src[e];
}

// ---------------- aggregation: T[n] = X[n] + sum_{e: dst==n} X[src[e]] ----------------
__global__ void agg_kernel(const float4* __restrict__ X, const int* __restrict__ row_start,
                           const int* __restrict__ deg, const int* __restrict__ csr_src,
                           float4* __restrict__ T) {
    int gid = blockIdx.x * blockDim.x + threadIdx.x;
    int n = gid >> 5;
    int c = gid & 31;
    if (n >= N_NODES) return;
    float4 acc = X[(size_t)n * 32 + c];   // self term (fuses x + agg)
    int rs = row_start[n];
    int d  = deg[n];
    int i = 0;
    for (; i + 4 <= d; i += 4) {
        int s0 = csr_src[rs + i + 0];
        int s1 = csr_src[rs + i + 1];
        int s2 = csr_src[rs + i + 2];
        int s3 = csr_src[rs + i + 3];
        float4 v0 = X[(size_t)s0 * 32 + c];
        float4 v1 = X[(size_t)s1 * 32 + c];
        float4 v2 = X[(size_t)s2 * 32 + c];
        float4 v3 = X[(size_t)s3 * 32 + c];
        acc.x += v0.x + v1.x + v2.x + v3.x;
        acc.y += v0.y + v1.y + v2.y + v3.y;
        acc.z += v0.z + v1.z + v2.z + v3.z;
        acc.w += v0.w + v1.w + v2.w + v3.w;
    }
    for (; i < d; ++i) {
        int s = csr_src[rs + i];
        float4 v = X[(size_t)s * 32 + c];
        acc.x += v.x; acc.y += v.y; acc.z += v.z; acc.w += v.w;
    }
    T[(size_t)n * 32 + c] = acc;
}

// ---------------- W prep: split fp32 W[k][n] into transposed bf16 hi/lo Wt[n][k] ----------------
// hi = truncate-to-bf16(w) (exact mantissa chop => lo = w - hi exact in fp32)
__global__ void wsplit_kernel(const float* __restrict__ W, unsigned short* __restrict__ Wh,
                              unsigned short* __restrict__ Wl) {
    int idx = blockIdx.x * blockDim.x + threadIdx.x;   // 16384
    if (idx >= HIDDEN * HIDDEN) return;
    int k = idx >> 7, n = idx & 127;
    float a = W[idx];
    unsigned u = __float_as_uint(a);
    unsigned hb = u & 0xffff0000u;
    float lo = a - __uint_as_float(hb);
    Wh[n * HIDDEN + k] = (unsigned short)(u >> 16);
    Wl[n * HIDDEN + k] = (unsigned short)(__float_as_uint(lo) >> 16);
}

// ---------------- MFMA split-bf16 matmul: C = act(A @ W + b) ----------------
// A: N x 128 fp32. Bh/Bl: Wt[n][k] bf16 (B^T rows => B-fragment = 8 contiguous k).
// Block tile 128(M) x 128(N): 4 waves, each 2 m-subtiles x 8 n-tiles of 16x16.
// A@W ~= Ah@Wh + Ah@Wl + Al@Wh  (drop Al@Wl, ~2^-16 rel)
__global__ __launch_bounds__(256)
void mm_mfma(const float* __restrict__ A, const unsigned short* __restrict__ Bh,
             const unsigned short* __restrict__ Bl, const float* __restrict__ bias,
             float* __restrict__ C, int relu) {
    int t = threadIdx.x;
    int w = t >> 6;
    int l = t & 63;
    int lane16 = l & 15;
    int quad = l >> 4;

    int row_base = blockIdx.x * 128 + w * 32;

    floatx4 acc[2][8];
    #pragma unroll
    for (int m = 0; m < 2; ++m)
        #pragma unroll
        for (int nt = 0; nt < 8; ++nt) acc[m][nt] = (floatx4){0.f, 0.f, 0.f, 0.f};

    #pragma unroll
    for (int kc = 0; kc < 4; ++kc) {
        int k0 = kc * 32 + quad * 8;
        // B fragments (global, L2-hot: whole W hi/lo = 64 KB)
        short8 bh[8], bl8[8];
        #pragma unroll
        for (int nt = 0; nt < 8; ++nt) {
            const unsigned short* ph = Bh + (nt * 16 + lane16) * HIDDEN + k0;
            const unsigned short* pl = Bl + (nt * 16 + lane16) * HIDDEN + k0;
            bh[nt]  = *(const short8*)ph;
            bl8[nt] = *(const short8*)pl;
        }
        // A fragments: load 8 fp32, split into bf16 hi/lo in-register
        short8 ahf[2], alf[2];
        #pragma unroll
        for (int m = 0; m < 2; ++m) {
            int r = row_base + m * 16 + lane16;
            float v[8];
            #pragma unroll
            for (int j = 0; j < 8; ++j) v[j] = 0.f;
            if (r < N_NODES) {
                const float4* p = (const float4*)(A + (size_t)r * HIDDEN + k0);
                float4 v0 = p[0], v1 = p[1];
                v[0] = v0.x; v[1] = v0.y; v[2] = v0.z; v[3] = v0.w;
                v[4] = v1.x; v[5] = v1.y; v[6] = v1.z; v[7] = v1.w;
            }
            short8 ah, al;
            #pragma unroll
            for (int j = 0; j < 8; ++j) {
                unsigned u = __float_as_uint(v[j]);
                unsigned hb = u & 0xffff0000u;
                float lo = v[j] - __uint_as_float(hb);
                ah[j] = (short)(u >> 16);
                al[j] = (short)(__float_as_uint(lo) >> 16);
            }
            ahf[m] = ah; alf[m] = al;
        }
        #pragma unroll
        for (int m = 0; m < 2; ++m)
            #pragma unroll
            for (int nt = 0; nt < 8; ++nt) {
                acc[m][nt] = __builtin_amdgcn_mfma_f32_16x16x32_bf16(ahf[m], bh[nt],  acc[m][nt], 0, 0, 0);
                acc[m][nt] = __builtin_amdgcn_mfma_f32_16x16x32_bf16(ahf[m], bl8[nt], acc[m][nt], 0, 0, 0);
                acc[m][nt] = __builtin_amdgcn_mfma_f32_16x16x32_bf16(alf[m], bh[nt],  acc[m][nt], 0, 0, 0);
            }
    }
    // epilogue: C/D layout col=lane&15, row=quad*4+reg
    #pragma unroll
    for (int nt = 0; nt < 8; ++nt) {
        int col = nt * 16 + lane16;
        float b = bias[col];
        #pragma unroll
        for (int m = 0; m < 2; ++m) {
            #pragma unroll
            for (int reg = 0; reg < 4; ++reg) {
                int r = row_base + m * 16 + quad * 4 + reg;
                if (r < N_NODES) {
                    float o = acc[m][nt][reg] + b;
                    if (relu) o = fmaxf(o, 0.f);
                    C[(size_t)r * HIDDEN + col] = o;
                }
            }
        }
    }
}

// ---------------- fused pool + mean + linear head ----------------
__global__ void pool_head_kernel(const float* __restrict__ H, const int* __restrict__ batch,
                                 const float* __restrict__ Wl, const float* __restrict__ bl,
                                 float* __restrict__ out) {
    int g = blockIdx.x;
    int t = threadIdx.x;   // 256 threads
    __shared__ int bounds[2];
    __shared__ float acc2[2 * HIDDEN];
    __shared__ float mean[HIDDEN];

    if (t < 2) {
        int target = g + t;
        int lo = 0, hi = N_NODES;
        while (lo < hi) {
            int mid = (lo + hi) >> 1;
            if (batch[mid] < target) lo = mid + 1; else hi = mid;
        }
        bounds[t] = lo;
    }
    __syncthreads();
    int r0 = bounds[0], r1 = bounds[1];

    int c = t & 127, half = t >> 7;
    float s = 0.f;
    for (int r = r0 + half; r < r1; r += 2)
        s += H[(size_t)r * HIDDEN + c];
    acc2[half * HIDDEN + c] = s;
    __syncthreads();
    if (t < HIDDEN) {
        float cntf = (float)(r1 - r0);
        mean[t] = (acc2[t] + acc2[HIDDEN + t]) / fmaxf(cntf, 1.0f);
    }
    __syncthreads();
    if (t < N_CLASSES) {
        float o = bl[t];
        #pragma unroll 8
        for (int k = 0; k < HIDDEN; ++k) o = fmaf(mean[k], Wl[k * N_CLASSES + t], o);
        out[(size_t)g * N_CLASSES + t] = o;
    }
}

extern "C" void kernel_launch(void* const* d_in, const int* in_sizes, int n_in,
                              void* d_out, int out_size, void* d_ws, size_t ws_size,
                              hipStream_t stream) {
    const float* x   = (const float*)d_in[0];
    const int*   ei  = (const int*)d_in[1];       // [2][N_EDGES]: row0=src, row1=dst
    const int*   bat = (const int*)d_in[2];
    const float* W1  = (const float*)d_in[3];
    const float* b1  = (const float*)d_in[4];
    const float* W2  = (const float*)d_in[5];
    const float* b2  = (const float*)d_in[6];
    const float* Wl  = (const float*)d_in[7];
    const float* bl  = (const float*)d_in[8];
    float* out = (float*)d_out;

    const int* src = ei;
    const int* dst = ei + N_EDGES;

    char* w = (char*)d_ws;
    size_t off = 0;
    auto alloc = [&](size_t bytes) { void* p = w + off; off = (off + bytes + 255) & ~(size_t)255; return p; };
    float* t_buf   = (float*)alloc((size_t)N_NODES * HIDDEN * 4);
    float* z_buf   = (float*)alloc((size_t)N_NODES * HIDDEN * 4);
    float* h_buf   = (float*)alloc((size_t)N_NODES * HIDDEN * 4);
    int*   deg     = (int*)  alloc((size_t)N_NODES * 4);
    int*   rowst   = (int*)  alloc((size_t)N_NODES * 4);
    int*   cursor  = (int*)  alloc((size_t)N_NODES * 4);
    int*   csr_src = (int*)  alloc((size_t)N_EDGES * 4);
    int*   counter = (int*)  alloc(256);
    unsigned short* w1h = (unsigned short*)alloc((size_t)HIDDEN * HIDDEN * 2);
    unsigned short* w1l = (unsigned short*)alloc((size_t)HIDDEN * HIDDEN * 2);
    unsigned short* w2h = (unsigned short*)alloc((size_t)HIDDEN * HIDDEN * 2);
    unsigned short* w2l = (unsigned short*)alloc((size_t)HIDDEN * HIDDEN * 2);
    (void)ws_size; (void)in_sizes; (void)n_in; (void)out_size;

    hipMemsetAsync(deg,     0, (size_t)N_NODES * 4, stream);
    hipMemsetAsync(cursor,  0, (size_t)N_NODES * 4, stream);
    hipMemsetAsync(counter, 0, 256, stream);

    // CSR build (once; reused by all 3 layers)
    deg_kernel<<<(N_EDGES + 255) / 256, 256, 0, stream>>>(dst, deg);
    offsets_kernel<<<(N_NODES + 255) / 256, 256, 0, stream>>>(deg, rowst, counter);
    fill_kernel<<<(N_EDGES + 255) / 256, 256, 0, stream>>>(src, dst, rowst, cursor, csr_src);

    // W split-transpose prep (once)
    wsplit_kernel<<<(HIDDEN * HIDDEN + 255) / 256, 256, 0, stream>>>(W1, w1h, w1l);
    wsplit_kernel<<<(HIDDEN * HIDDEN + 255) / 256, 256, 0, stream>>>(W2, w2h, w2l);

    const int agg_grid = (N_NODES * 32 + 255) / 256;
    const int mm_grid  = (N_NODES + 127) / 128;

    // layer 1 (input x)
    agg_kernel<<<agg_grid, 256, 0, stream>>>((const float4*)x, rowst, deg, csr_src, (float4*)t_buf);
    mm_mfma<<<mm_grid, 256, 0, stream>>>(t_buf, w1h, w1l, b1, z_buf, 1);
    mm_mfma<<<mm_grid, 256, 0, stream>>>(z_buf, w2h, w2l, b2, h_buf, 1);
    // layer 2
    agg_kernel<<<agg_grid, 256, 0, stream>>>((const float4*)h_buf, rowst, deg, csr_src, (float4*)t_buf);
    mm_mfma<<<mm_grid, 256, 0, stream>>>(t_buf, w1h, w1l, b1, z_buf, 1);
    mm_mfma<<<mm_grid, 256, 0, stream>>>(z_buf, w2h, w2l, b2, h_buf, 1);
    // layer 3 (no outer relu)
    agg_kernel<<<agg_grid, 256, 0, stream>>>((const float4*)h_buf, rowst, deg, csr_src, (float4*)t_buf);
    mm_mfma<<<mm_grid, 256, 0, stream>>>(t_buf, w1h, w1l, b1, z_buf, 1);
    mm_mfma<<<mm_grid, 256, 0, stream>>>(z_buf, w2h, w2l, b2, h_buf, 0);

    // fused mean-pool + head (batch sorted -> binary-search boundaries, no atomics)
    pool_head_kernel<<<N_GRAPHS, 256, 0, stream>>>(h_buf, bat, Wl, bl, out);
}

// Round 4
// 426.930 us; speedup vs baseline: 1.7869x; 1.3080x over previous
//
#include <hip/hip_runtime.h>

#define N_NODES  50000
#define N_EDGES  800000
#define HIDDEN   128
#define N_GRAPHS 256
#define N_CLASSES 10
#define WLD 136   // padded LDS leading dim for W tiles (bank shift 4/row -> 2-way max, free)

typedef short short8 __attribute__((ext_vector_type(8)));
typedef float floatx4 __attribute__((ext_vector_type(4)));

__device__ inline unsigned short bf16_rtne(float x) {
    unsigned u = __float_as_uint(x);
    unsigned r = ((u >> 16) & 1u) + 0x7fffu;
    return (unsigned short)((u + r) >> 16);
}

// ---------------- CSR build ----------------
__global__ void deg_kernel(const int* __restrict__ dst, int* __restrict__ deg) {
    int e = blockIdx.x * blockDim.x + threadIdx.x;
    if (e < N_EDGES) atomicAdd(&deg[dst[e]], 1);
}

__global__ void offsets_kernel(const int* __restrict__ deg, int* __restrict__ row_start,
                               int* __restrict__ counter) {
    int n = blockIdx.x * blockDim.x + threadIdx.x;
    int d = (n < N_NODES) ? deg[n] : 0;
    int lane = threadIdx.x & 63;
    int incl = d;
    #pragma unroll
    for (int off = 1; off < 64; off <<= 1) {
        int v = __shfl_up(incl, off, 64);
        if (lane >= off) incl += v;
    }
    int excl = incl - d;
    int total = __shfl(incl, 63, 64);
    int base = 0;
    if (lane == 0) base = atomicAdd(counter, total);
    base = __shfl(base, 0, 64);
    if (n < N_NODES) row_start[n] = base + excl;
}

__global__ void fill_kernel(const int* __restrict__ src, const int* __restrict__ dst,
                            const int* __restrict__ row_start, int* __restrict__ cursor,
                            int* __restrict__ csr_src) {
    int e = blockIdx.x * blockDim.x + threadIdx.x;
    if (e >= N_EDGES) return;
    int d = dst[e];
    int pos = row_start[d] + atomicAdd(&cursor[d], 1);
    csr_src[pos] = src[e];
}

// ---------------- x -> bf16 convert (once) ----------------
__global__ void xconv_kernel(const float4* __restrict__ X, uint4* __restrict__ Xb) {
    int i = blockIdx.x * blockDim.x + threadIdx.x;   // over uint4 = 8 bf16
    if (i >= N_NODES * HIDDEN / 8) return;
    float4 a = X[2 * i], b = X[2 * i + 1];
    uint4 o;
    o.x = (unsigned)bf16_rtne(a.x) | ((unsigned)bf16_rtne(a.y) << 16);
    o.y = (unsigned)bf16_rtne(a.z) | ((unsigned)bf16_rtne(a.w) << 16);
    o.z = (unsigned)bf16_rtne(b.x) | ((unsigned)bf16_rtne(b.y) << 16);
    o.w = (unsigned)bf16_rtne(b.z) | ((unsigned)bf16_rtne(b.w) << 16);
    Xb[i] = o;
}

// ---------------- aggregation (bf16 gather): T[n] = Xb[n] + sum Xb[src] ----------------
// one 16-lane group per node; lane = uint4 chunk (16 * 16B = 256B bf16 row); fp32 accumulate
__device__ inline void acc_bf2(unsigned d, float& f0, float& f1) {
    f0 += __uint_as_float(d << 16);
    f1 += __uint_as_float(d & 0xffff0000u);
}

__global__ void agg_kernel(const uint4* __restrict__ Xb, const int* __restrict__ row_start,
                           const int* __restrict__ deg, const int* __restrict__ csr_src,
                           float4* __restrict__ T) {
    int gid = blockIdx.x * blockDim.x + threadIdx.x;
    int n = gid >> 4;
    int c = gid & 15;
    if (n >= N_NODES) return;
    float a[8];
    #pragma unroll
    for (int j = 0; j < 8; ++j) a[j] = 0.f;
    {   // self term
        uint4 v = Xb[(size_t)n * 16 + c];
        acc_bf2(v.x, a[0], a[1]); acc_bf2(v.y, a[2], a[3]);
        acc_bf2(v.z, a[4], a[5]); acc_bf2(v.w, a[6], a[7]);
    }
    int rs = row_start[n];
    int d  = deg[n];
    int i = 0;
    for (; i + 4 <= d; i += 4) {
        int s0 = csr_src[rs + i + 0];
        int s1 = csr_src[rs + i + 1];
        int s2 = csr_src[rs + i + 2];
        int s3 = csr_src[rs + i + 3];
        uint4 v0 = Xb[(size_t)s0 * 16 + c];
        uint4 v1 = Xb[(size_t)s1 * 16 + c];
        uint4 v2 = Xb[(size_t)s2 * 16 + c];
        uint4 v3 = Xb[(size_t)s3 * 16 + c];
        acc_bf2(v0.x, a[0], a[1]); acc_bf2(v0.y, a[2], a[3]); acc_bf2(v0.z, a[4], a[5]); acc_bf2(v0.w, a[6], a[7]);
        acc_bf2(v1.x, a[0], a[1]); acc_bf2(v1.y, a[2], a[3]); acc_bf2(v1.z, a[4], a[5]); acc_bf2(v1.w, a[6], a[7]);
        acc_bf2(v2.x, a[0], a[1]); acc_bf2(v2.y, a[2], a[3]); acc_bf2(v2.z, a[4], a[5]); acc_bf2(v2.w, a[6], a[7]);
        acc_bf2(v3.x, a[0], a[1]); acc_bf2(v3.y, a[2], a[3]); acc_bf2(v3.z, a[4], a[5]); acc_bf2(v3.w, a[6], a[7]);
    }
    for (; i < d; ++i) {
        int s = csr_src[rs + i];
        uint4 v = Xb[(size_t)s * 16 + c];
        acc_bf2(v.x, a[0], a[1]); acc_bf2(v.y, a[2], a[3]);
        acc_bf2(v.z, a[4], a[5]); acc_bf2(v.w, a[6], a[7]);
    }
    T[(size_t)n * 32 + c * 2 + 0] = make_float4(a[0], a[1], a[2], a[3]);
    T[(size_t)n * 32 + c * 2 + 1] = make_float4(a[4], a[5], a[6], a[7]);
}

// ---------------- W prep: split fp32 W[k][n] into transposed bf16 hi/lo Wt[n][k] ----------------
__global__ void wsplit_kernel(const float* __restrict__ W, unsigned short* __restrict__ Wh,
                              unsigned short* __restrict__ Wl) {
    int idx = blockIdx.x * blockDim.x + threadIdx.x;   // 16384
    if (idx >= HIDDEN * HIDDEN) return;
    int k = idx >> 7, n = idx & 127;
    float a = W[idx];
    unsigned u = __float_as_uint(a);
    unsigned hb = u & 0xffff0000u;
    float lo = a - __uint_as_float(hb);
    Wh[n * HIDDEN + k] = (unsigned short)(u >> 16);
    Wl[n * HIDDEN + k] = (unsigned short)(__float_as_uint(lo) >> 16);
}

// ---------------- MFMA split-bf16 matmul: out = act(A @ W + b) ----------------
// W hi/lo staged in LDS (padded). A: fp32, split in-register.
// A@W ~= Ah@Wh + Ah@Wl + Al@Wh  (drop Al@Wl, ~2^-16 rel)
// Writes fp32 C (if non-null) and/or bf16 Cb (if non-null).
__global__ __launch_bounds__(256)
void mm_mfma(const float* __restrict__ A, const unsigned short* __restrict__ Bh,
             const unsigned short* __restrict__ Bl, const float* __restrict__ bias,
             float* __restrict__ C, unsigned short* __restrict__ Cb, int relu) {
    __shared__ unsigned short WhS[HIDDEN * WLD];   // 34.8 KB
    __shared__ unsigned short WlS[HIDDEN * WLD];   // 34.8 KB

    int t = threadIdx.x;
    {   // stage W hi/lo: 2048 ushort8 each, 8 per thread, coalesced global reads
        const short8* gh = (const short8*)Bh;
        const short8* gl = (const short8*)Bl;
        #pragma unroll
        for (int i = 0; i < 8; ++i) {
            int idx = i * 256 + t;              // ushort8 index 0..2047
            int row = idx >> 4, kk = (idx & 15) * 8;
            *(short8*)(WhS + row * WLD + kk) = gh[idx];
            *(short8*)(WlS + row * WLD + kk) = gl[idx];
        }
    }
    __syncthreads();

    int w = t >> 6;
    int l = t & 63;
    int lane16 = l & 15;
    int quad = l >> 4;
    int row_base = blockIdx.x * 128 + w * 32;

    floatx4 acc[2][8];
    #pragma unroll
    for (int m = 0; m < 2; ++m)
        #pragma unroll
        for (int nt = 0; nt < 8; ++nt) acc[m][nt] = (floatx4){0.f, 0.f, 0.f, 0.f};

    #pragma unroll
    for (int kc = 0; kc < 4; ++kc) {
        int k0 = kc * 32 + quad * 8;
        // A fragments first (global latency), split while B LDS reads land
        short8 ahf[2], alf[2];
        #pragma unroll
        for (int m = 0; m < 2; ++m) {
            int r = row_base + m * 16 + lane16;
            float v[8];
            #pragma unroll
            for (int j = 0; j < 8; ++j) v[j] = 0.f;
            if (r < N_NODES) {
                const float4* p = (const float4*)(A + (size_t)r * HIDDEN + k0);
                float4 v0 = p[0], v1 = p[1];
                v[0] = v0.x; v[1] = v0.y; v[2] = v0.z; v[3] = v0.w;
                v[4] = v1.x; v[5] = v1.y; v[6] = v1.z; v[7] = v1.w;
            }
            short8 ah, al;
            #pragma unroll
            for (int j = 0; j < 8; ++j) {
                unsigned u = __float_as_uint(v[j]);
                unsigned hb = u & 0xffff0000u;
                float lo = v[j] - __uint_as_float(hb);
                ah[j] = (short)(u >> 16);
                al[j] = (short)(__float_as_uint(lo) >> 16);
            }
            ahf[m] = ah; alf[m] = al;
        }
        // B fragments from LDS (b128, 2-way bank alias only)
        short8 bh[8], bl8[8];
        #pragma unroll
        for (int nt = 0; nt < 8; ++nt) {
            bh[nt]  = *(const short8*)(WhS + (nt * 16 + lane16) * WLD + k0);
            bl8[nt] = *(const short8*)(WlS + (nt * 16 + lane16) * WLD + k0);
        }
        #pragma unroll
        for (int m = 0; m < 2; ++m)
            #pragma unroll
            for (int nt = 0; nt < 8; ++nt) {
                acc[m][nt] = __builtin_amdgcn_mfma_f32_16x16x32_bf16(ahf[m], bh[nt],  acc[m][nt], 0, 0, 0);
                acc[m][nt] = __builtin_amdgcn_mfma_f32_16x16x32_bf16(ahf[m], bl8[nt], acc[m][nt], 0, 0, 0);
                acc[m][nt] = __builtin_amdgcn_mfma_f32_16x16x32_bf16(alf[m], bh[nt],  acc[m][nt], 0, 0, 0);
            }
    }
    // epilogue: C/D layout col=lane&15, row=quad*4+reg
    #pragma unroll
    for (int nt = 0; nt < 8; ++nt) {
        int col = nt * 16 + lane16;
        float b = bias[col];
        #pragma unroll
        for (int m = 0; m < 2; ++m) {
            #pragma unroll
            for (int reg = 0; reg < 4; ++reg) {
                int r = row_base + m * 16 + quad * 4 + reg;
                if (r < N_NODES) {
                    float o = acc[m][nt][reg] + b;
                    if (relu) o = fmaxf(o, 0.f);
                    if (C)  C[(size_t)r * HIDDEN + col] = o;
                    if (Cb) Cb[(size_t)r * HIDDEN + col] = bf16_rtne(o);
                }
            }
        }
    }
}

// ---------------- fused pool + mean + linear head ----------------
__global__ void pool_head_kernel(const float* __restrict__ H, const int* __restrict__ batch,
                                 const float* __restrict__ Wl, const float* __restrict__ bl,
                                 float* __restrict__ out) {
    int g = blockIdx.x;
    int t = threadIdx.x;   // 256 threads
    __shared__ int bounds[2];
    __shared__ float acc2[2 * HIDDEN];
    __shared__ float mean[HIDDEN];

    if (t < 2) {
        int target = g + t;
        int lo = 0, hi = N_NODES;
        while (lo < hi) {
            int mid = (lo + hi) >> 1;
            if (batch[mid] < target) lo = mid + 1; else hi = mid;
        }
        bounds[t] = lo;
    }
    __syncthreads();
    int r0 = bounds[0], r1 = bounds[1];

    int c = t & 127, half = t >> 7;
    float s = 0.f;
    for (int r = r0 + half; r < r1; r += 2)
        s += H[(size_t)r * HIDDEN + c];
    acc2[half * HIDDEN + c] = s;
    __syncthreads();
    if (t < HIDDEN) {
        float cntf = (float)(r1 - r0);
        mean[t] = (acc2[t] + acc2[HIDDEN + t]) / fmaxf(cntf, 1.0f);
    }
    __syncthreads();
    if (t < N_CLASSES) {
        float o = bl[t];
        #pragma unroll 8
        for (int k = 0; k < HIDDEN; ++k) o = fmaf(mean[k], Wl[k * N_CLASSES + t], o);
        out[(size_t)g * N_CLASSES + t] = o;
    }
}

extern "C" void kernel_launch(void* const* d_in, const int* in_sizes, int n_in,
                              void* d_out, int out_size, void* d_ws, size_t ws_size,
                              hipStream_t stream) {
    const float* x   = (const float*)d_in[0];
    const int*   ei  = (const int*)d_in[1];       // [2][N_EDGES]: row0=src, row1=dst
    const int*   bat = (const int*)d_in[2];
    const float* W1  = (const float*)d_in[3];
    const float* b1  = (const float*)d_in[4];
    const float* W2  = (const float*)d_in[5];
    const float* b2  = (const float*)d_in[6];
    const float* Wl  = (const float*)d_in[7];
    const float* bl  = (const float*)d_in[8];
    float* out = (float*)d_out;

    const int* src = ei;
    const int* dst = ei + N_EDGES;

    char* w = (char*)d_ws;
    size_t off = 0;
    auto alloc = [&](size_t bytes) { void* p = w + off; off = (off + bytes + 255) & ~(size_t)255; return p; };
    float* t_buf   = (float*)alloc((size_t)N_NODES * HIDDEN * 4);
    float* z_buf   = (float*)alloc((size_t)N_NODES * HIDDEN * 4);
    float* h_buf   = (float*)alloc((size_t)N_NODES * HIDDEN * 4);
    unsigned short* g_bf = (unsigned short*)alloc((size_t)N_NODES * HIDDEN * 2);  // bf16 gather table
    int*   deg     = (int*)  alloc((size_t)N_NODES * 4);
    int*   rowst   = (int*)  alloc((size_t)N_NODES * 4);
    int*   cursor  = (int*)  alloc((size_t)N_NODES * 4);
    int*   csr_src = (int*)  alloc((size_t)N_EDGES * 4);
    int*   counter = (int*)  alloc(256);
    unsigned short* w1h = (unsigned short*)alloc((size_t)HIDDEN * HIDDEN * 2);
    unsigned short* w1l = (unsigned short*)alloc((size_t)HIDDEN * HIDDEN * 2);
    unsigned short* w2h = (unsigned short*)alloc((size_t)HIDDEN * HIDDEN * 2);
    unsigned short* w2l = (unsigned short*)alloc((size_t)HIDDEN * HIDDEN * 2);
    (void)ws_size; (void)in_sizes; (void)n_in; (void)out_size;

    hipMemsetAsync(deg,     0, (size_t)N_NODES * 4, stream);
    hipMemsetAsync(cursor,  0, (size_t)N_NODES * 4, stream);
    hipMemsetAsync(counter, 0, 256, stream);

    // CSR build (once; reused by all 3 layers)
    deg_kernel<<<(N_EDGES + 255) / 256, 256, 0, stream>>>(dst, deg);
    offsets_kernel<<<(N_NODES + 255) / 256, 256, 0, stream>>>(deg, rowst, counter);
    fill_kernel<<<(N_EDGES + 255) / 256, 256, 0, stream>>>(src, dst, rowst, cursor, csr_src);

    // W split-transpose prep (once) + x -> bf16
    wsplit_kernel<<<(HIDDEN * HIDDEN + 255) / 256, 256, 0, stream>>>(W1, w1h, w1l);
    wsplit_kernel<<<(HIDDEN * HIDDEN + 255) / 256, 256, 0, stream>>>(W2, w2h, w2l);
    xconv_kernel<<<(N_NODES * HIDDEN / 8 + 255) / 256, 256, 0, stream>>>((const float4*)x, (uint4*)g_bf);

    const int agg_grid = (N_NODES * 16 + 255) / 256;
    const int mm_grid  = (N_NODES + 127) / 128;

    // layer 1
    agg_kernel<<<agg_grid, 256, 0, stream>>>((const uint4*)g_bf, rowst, deg, csr_src, (float4*)t_buf);
    mm_mfma<<<mm_grid, 256, 0, stream>>>(t_buf, w1h, w1l, b1, z_buf, (unsigned short*)nullptr, 1);
    mm_mfma<<<mm_grid, 256, 0, stream>>>(z_buf, w2h, w2l, b2, (float*)nullptr, g_bf, 1);
    // layer 2
    agg_kernel<<<agg_grid, 256, 0, stream>>>((const uint4*)g_bf, rowst, deg, csr_src, (float4*)t_buf);
    mm_mfma<<<mm_grid, 256, 0, stream>>>(t_buf, w1h, w1l, b1, z_buf, (unsigned short*)nullptr, 1);
    mm_mfma<<<mm_grid, 256, 0, stream>>>(z_buf, w2h, w2l, b2, (float*)nullptr, g_bf, 1);
    // layer 3 (no outer relu; fp32 h for pooling)
    agg_kernel<<<agg_grid, 256, 0, stream>>>((const uint4*)g_bf, rowst, deg, csr_src, (float4*)t_buf);
    mm_mfma<<<mm_grid, 256, 0, stream>>>(t_buf, w1h, w1l, b1, z_buf, (unsigned short*)nullptr, 1);
    mm_mfma<<<mm_grid, 256, 0, stream>>>(z_buf, w2h, w2l, b2, h_buf, (unsigned short*)nullptr, 0);

    // fused mean-pool + head
    pool_head_kernel<<<N_GRAPHS, 256, 0, stream>>>(h_buf, bat, Wl, bl, out);
}

// Round 5
// 404.155 us; speedup vs baseline: 1.8876x; 1.0564x over previous
//
#include <hip/hip_runtime.h>

#define N_NODES  50000
#define N_EDGES  800000
#define HIDDEN   128
#define N_GRAPHS 256
#define N_CLASSES 10
#define WLD 136   // padded LDS leading dim for W tiles (bank shift 4/row -> 2-way max, free)

typedef short short8 __attribute__((ext_vector_type(8)));
typedef float floatx4 __attribute__((ext_vector_type(4)));

__device__ inline unsigned short bf16_rtne(float x) {
    unsigned u = __float_as_uint(x);
    unsigned r = ((u >> 16) & 1u) + 0x7fffu;
    return (unsigned short)((u + r) >> 16);
}

// split fp32 into bf16 hi (truncate) + bf16 lo (truncated residual)
__device__ inline void bf16_split(float a, unsigned short& hi, unsigned short& lo) {
    unsigned u = __float_as_uint(a);
    hi = (unsigned short)(u >> 16);
    float res = a - __uint_as_float(u & 0xffff0000u);
    lo = (unsigned short)(__float_as_uint(res) >> 16);
}

// ---------------- CSR build: ONE atomic pass ----------------
// epos[e] = slot of edge e within its dst row; deg accumulates degrees.
__global__ void count_pos_kernel(const int* __restrict__ dst, int* __restrict__ deg,
                                 int* __restrict__ epos) {
    int e = blockIdx.x * blockDim.x + threadIdx.x;
    if (e < N_EDGES) epos[e] = atomicAdd(&deg[dst[e]], 1);
}

__global__ void offsets_kernel(const int* __restrict__ deg, int* __restrict__ row_start,
                               int* __restrict__ counter) {
    int n = blockIdx.x * blockDim.x + threadIdx.x;
    int d = (n < N_NODES) ? deg[n] : 0;
    int lane = threadIdx.x & 63;
    int incl = d;
    #pragma unroll
    for (int off = 1; off < 64; off <<= 1) {
        int v = __shfl_up(incl, off, 64);
        if (lane >= off) incl += v;
    }
    int excl = incl - d;
    int total = __shfl(incl, 63, 64);
    int base = 0;
    if (lane == 0) base = atomicAdd(counter, total);
    base = __shfl(base, 0, 64);
    if (n < N_NODES) row_start[n] = base + excl;
}

// atomic-free scatter
__global__ void place_kernel(const int* __restrict__ src, const int* __restrict__ dst,
                             const int* __restrict__ epos, const int* __restrict__ row_start,
                             int* __restrict__ csr_src) {
    int e = blockIdx.x * blockDim.x + threadIdx.x;
    if (e >= N_EDGES) return;
    csr_src[row_start[dst[e]] + epos[e]] = src[e];
}

// ---------------- x -> bf16 convert (once) ----------------
__global__ void xconv_kernel(const float4* __restrict__ X, uint4* __restrict__ Xb) {
    int i = blockIdx.x * blockDim.x + threadIdx.x;   // over uint4 = 8 bf16
    if (i >= N_NODES * HIDDEN / 8) return;
    float4 a = X[2 * i], b = X[2 * i + 1];
    uint4 o;
    o.x = (unsigned)bf16_rtne(a.x) | ((unsigned)bf16_rtne(a.y) << 16);
    o.y = (unsigned)bf16_rtne(a.z) | ((unsigned)bf16_rtne(a.w) << 16);
    o.z = (unsigned)bf16_rtne(b.x) | ((unsigned)bf16_rtne(b.y) << 16);
    o.w = (unsigned)bf16_rtne(b.z) | ((unsigned)bf16_rtne(b.w) << 16);
    Xb[i] = o;
}

// ---------------- aggregation (bf16 gather): T = Xb[n] + sum Xb[src], pre-split hi/lo out ----------------
__device__ inline void acc_bf2(unsigned d, float& f0, float& f1) {
    f0 += __uint_as_float(d << 16);
    f1 += __uint_as_float(d & 0xffff0000u);
}

__global__ void agg_kernel(const uint4* __restrict__ Xb, const int* __restrict__ row_start,
                           const int* __restrict__ deg, const int* __restrict__ csr_src,
                           uint4* __restrict__ Th, uint4* __restrict__ Tl) {
    int gid = blockIdx.x * blockDim.x + threadIdx.x;
    int n = gid >> 4;
    int c = gid & 15;
    if (n >= N_NODES) return;
    float a[8];
    #pragma unroll
    for (int j = 0; j < 8; ++j) a[j] = 0.f;
    {   // self term
        uint4 v = Xb[(size_t)n * 16 + c];
        acc_bf2(v.x, a[0], a[1]); acc_bf2(v.y, a[2], a[3]);
        acc_bf2(v.z, a[4], a[5]); acc_bf2(v.w, a[6], a[7]);
    }
    int rs = row_start[n];
    int d  = deg[n];
    int i = 0;
    for (; i + 4 <= d; i += 4) {
        int s0 = csr_src[rs + i + 0];
        int s1 = csr_src[rs + i + 1];
        int s2 = csr_src[rs + i + 2];
        int s3 = csr_src[rs + i + 3];
        uint4 v0 = Xb[(size_t)s0 * 16 + c];
        uint4 v1 = Xb[(size_t)s1 * 16 + c];
        uint4 v2 = Xb[(size_t)s2 * 16 + c];
        uint4 v3 = Xb[(size_t)s3 * 16 + c];
        acc_bf2(v0.x, a[0], a[1]); acc_bf2(v0.y, a[2], a[3]); acc_bf2(v0.z, a[4], a[5]); acc_bf2(v0.w, a[6], a[7]);
        acc_bf2(v1.x, a[0], a[1]); acc_bf2(v1.y, a[2], a[3]); acc_bf2(v1.z, a[4], a[5]); acc_bf2(v1.w, a[6], a[7]);
        acc_bf2(v2.x, a[0], a[1]); acc_bf2(v2.y, a[2], a[3]); acc_bf2(v2.z, a[4], a[5]); acc_bf2(v2.w, a[6], a[7]);
        acc_bf2(v3.x, a[0], a[1]); acc_bf2(v3.y, a[2], a[3]); acc_bf2(v3.z, a[4], a[5]); acc_bf2(v3.w, a[6], a[7]);
    }
    for (; i < d; ++i) {
        int s = csr_src[rs + i];
        uint4 v = Xb[(size_t)s * 16 + c];
        acc_bf2(v.x, a[0], a[1]); acc_bf2(v.y, a[2], a[3]);
        acc_bf2(v.z, a[4], a[5]); acc_bf2(v.w, a[6], a[7]);
    }
    // pre-split hi/lo for the MFMA consumer
    unsigned short hi[8], lo[8];
    #pragma unroll
    for (int j = 0; j < 8; ++j) bf16_split(a[j], hi[j], lo[j]);
    uint4 oh, ol;
    oh.x = (unsigned)hi[0] | ((unsigned)hi[1] << 16);
    oh.y = (unsigned)hi[2] | ((unsigned)hi[3] << 16);
    oh.z = (unsigned)hi[4] | ((unsigned)hi[5] << 16);
    oh.w = (unsigned)hi[6] | ((unsigned)hi[7] << 16);
    ol.x = (unsigned)lo[0] | ((unsigned)lo[1] << 16);
    ol.y = (unsigned)lo[2] | ((unsigned)lo[3] << 16);
    ol.z = (unsigned)lo[4] | ((unsigned)lo[5] << 16);
    ol.w = (unsigned)lo[6] | ((unsigned)lo[7] << 16);
    Th[(size_t)n * 16 + c] = oh;
    Tl[(size_t)n * 16 + c] = ol;
}

// ---------------- W prep: split fp32 W[k][n] into transposed bf16 hi/lo Wt[n][k] ----------------
__global__ void wsplit_kernel(const float* __restrict__ W, unsigned short* __restrict__ Wh,
                              unsigned short* __restrict__ Wl) {
    int idx = blockIdx.x * blockDim.x + threadIdx.x;   // 16384
    if (idx >= HIDDEN * HIDDEN) return;
    int k = idx >> 7, n = idx & 127;
    unsigned short hi, lo;
    bf16_split(W[idx], hi, lo);
    Wh[n * HIDDEN + k] = hi;
    Wl[n * HIDDEN + k] = lo;
}

// ---------------- MFMA split-bf16 matmul: out = act(A @ W + b) ----------------
// A pre-split (Ah, Al) bf16 row-major. W hi/lo staged in LDS (padded).
// A@W ~= Ah@Wh + Ah@Wl + Al@Wh (drop Al@Wl). Outputs (any subset):
//   C   : fp32
//   Ch/Cl: pre-split bf16 hi/lo (feeds next mm)
//   Cb  : rtne bf16 (feeds next gather)
__global__ __launch_bounds__(256)
void mm_mfma(const unsigned short* __restrict__ Ah, const unsigned short* __restrict__ Al,
             const unsigned short* __restrict__ Bh, const unsigned short* __restrict__ Bl,
             const float* __restrict__ bias,
             float* __restrict__ C, unsigned short* __restrict__ Ch,
             unsigned short* __restrict__ Cl, unsigned short* __restrict__ Cb, int relu) {
    __shared__ unsigned short WhS[HIDDEN * WLD];   // 34.8 KB
    __shared__ unsigned short WlS[HIDDEN * WLD];   // 34.8 KB

    int t = threadIdx.x;
    {   // stage W hi/lo: 2048 ushort8 each, 8 per thread, coalesced global reads
        const short8* gh = (const short8*)Bh;
        const short8* gl = (const short8*)Bl;
        #pragma unroll
        for (int i = 0; i < 8; ++i) {
            int idx = i * 256 + t;              // ushort8 index 0..2047
            int row = idx >> 4, kk = (idx & 15) * 8;
            *(short8*)(WhS + row * WLD + kk) = gh[idx];
            *(short8*)(WlS + row * WLD + kk) = gl[idx];
        }
    }
    __syncthreads();

    int w = t >> 6;
    int l = t & 63;
    int lane16 = l & 15;
    int quad = l >> 4;
    int row_base = blockIdx.x * 128 + w * 32;

    floatx4 acc[2][8];
    #pragma unroll
    for (int m = 0; m < 2; ++m)
        #pragma unroll
        for (int nt = 0; nt < 8; ++nt) acc[m][nt] = (floatx4){0.f, 0.f, 0.f, 0.f};

    #pragma unroll
    for (int kc = 0; kc < 4; ++kc) {
        int k0 = kc * 32 + quad * 8;
        short8 ahf[2], alf[2];
        #pragma unroll
        for (int m = 0; m < 2; ++m) {
            int r = row_base + m * 16 + lane16;
            if (r < N_NODES) {
                ahf[m] = *(const short8*)(Ah + (size_t)r * HIDDEN + k0);
                alf[m] = *(const short8*)(Al + (size_t)r * HIDDEN + k0);
            } else {
                ahf[m] = (short8){0,0,0,0,0,0,0,0};
                alf[m] = (short8){0,0,0,0,0,0,0,0};
            }
        }
        short8 bh[8], bl8[8];
        #pragma unroll
        for (int nt = 0; nt < 8; ++nt) {
            bh[nt]  = *(const short8*)(WhS + (nt * 16 + lane16) * WLD + k0);
            bl8[nt] = *(const short8*)(WlS + (nt * 16 + lane16) * WLD + k0);
        }
        #pragma unroll
        for (int m = 0; m < 2; ++m)
            #pragma unroll
            for (int nt = 0; nt < 8; ++nt) {
                acc[m][nt] = __builtin_amdgcn_mfma_f32_16x16x32_bf16(ahf[m], bh[nt],  acc[m][nt], 0, 0, 0);
                acc[m][nt] = __builtin_amdgcn_mfma_f32_16x16x32_bf16(ahf[m], bl8[nt], acc[m][nt], 0, 0, 0);
                acc[m][nt] = __builtin_amdgcn_mfma_f32_16x16x32_bf16(alf[m], bh[nt],  acc[m][nt], 0, 0, 0);
            }
    }
    // epilogue: C/D layout col=lane&15, row=quad*4+reg
    #pragma unroll
    for (int nt = 0; nt < 8; ++nt) {
        int col = nt * 16 + lane16;
        float b = bias[col];
        #pragma unroll
        for (int m = 0; m < 2; ++m) {
            #pragma unroll
            for (int reg = 0; reg < 4; ++reg) {
                int r = row_base + m * 16 + quad * 4 + reg;
                if (r < N_NODES) {
                    float o = acc[m][nt][reg] + b;
                    if (relu) o = fmaxf(o, 0.f);
                    size_t oi = (size_t)r * HIDDEN + col;
                    if (C) C[oi] = o;
                    if (Ch) {
                        unsigned short hi, lo;
                        bf16_split(o, hi, lo);
                        Ch[oi] = hi; Cl[oi] = lo;
                    }
                    if (Cb) Cb[oi] = bf16_rtne(o);
                }
            }
        }
    }
}

// ---------------- fused pool + mean + linear head ----------------
__global__ void pool_head_kernel(const float* __restrict__ H, const int* __restrict__ batch,
                                 const float* __restrict__ Wl, const float* __restrict__ bl,
                                 float* __restrict__ out) {
    int g = blockIdx.x;
    int t = threadIdx.x;   // 256 threads
    __shared__ int bounds[2];
    __shared__ float acc2[2 * HIDDEN];
    __shared__ float mean[HIDDEN];

    if (t < 2) {
        int target = g + t;
        int lo = 0, hi = N_NODES;
        while (lo < hi) {
            int mid = (lo + hi) >> 1;
            if (batch[mid] < target) lo = mid + 1; else hi = mid;
        }
        bounds[t] = lo;
    }
    __syncthreads();
    int r0 = bounds[0], r1 = bounds[1];

    int c = t & 127, half = t >> 7;
    float s = 0.f;
    for (int r = r0 + half; r < r1; r += 2)
        s += H[(size_t)r * HIDDEN + c];
    acc2[half * HIDDEN + c] = s;
    __syncthreads();
    if (t < HIDDEN) {
        float cntf = (float)(r1 - r0);
        mean[t] = (acc2[t] + acc2[HIDDEN + t]) / fmaxf(cntf, 1.0f);
    }
    __syncthreads();
    if (t < N_CLASSES) {
        float o = bl[t];
        #pragma unroll 8
        for (int k = 0; k < HIDDEN; ++k) o = fmaf(mean[k], Wl[k * N_CLASSES + t], o);
        out[(size_t)g * N_CLASSES + t] = o;
    }
}

extern "C" void kernel_launch(void* const* d_in, const int* in_sizes, int n_in,
                              void* d_out, int out_size, void* d_ws, size_t ws_size,
                              hipStream_t stream) {
    const float* x   = (const float*)d_in[0];
    const int*   ei  = (const int*)d_in[1];       // [2][N_EDGES]: row0=src, row1=dst
    const int*   bat = (const int*)d_in[2];
    const float* W1  = (const float*)d_in[3];
    const float* b1  = (const float*)d_in[4];
    const float* W2  = (const float*)d_in[5];
    const float* b2  = (const float*)d_in[6];
    const float* Wl  = (const float*)d_in[7];
    const float* bl  = (const float*)d_in[8];
    float* out = (float*)d_out;

    const int* src = ei;
    const int* dst = ei + N_EDGES;

    char* w = (char*)d_ws;
    size_t off = 0;
    auto alloc = [&](size_t bytes) { void* p = w + off; off = (off + bytes + 255) & ~(size_t)255; return p; };
    unsigned short* th_buf = (unsigned short*)alloc((size_t)N_NODES * HIDDEN * 2);
    unsigned short* tl_buf = (unsigned short*)alloc((size_t)N_NODES * HIDDEN * 2);
    unsigned short* zh_buf = (unsigned short*)alloc((size_t)N_NODES * HIDDEN * 2);
    unsigned short* zl_buf = (unsigned short*)alloc((size_t)N_NODES * HIDDEN * 2);
    float* h_buf   = (float*)alloc((size_t)N_NODES * HIDDEN * 4);
    unsigned short* g_bf = (unsigned short*)alloc((size_t)N_NODES * HIDDEN * 2);  // bf16 gather table
    int*   deg     = (int*)  alloc((size_t)N_NODES * 4);
    int*   rowst   = (int*)  alloc((size_t)N_NODES * 4);
    int*   epos    = (int*)  alloc((size_t)N_EDGES * 4);
    int*   csr_src = (int*)  alloc((size_t)N_EDGES * 4);
    int*   counter = (int*)  alloc(256);
    unsigned short* w1h = (unsigned short*)alloc((size_t)HIDDEN * HIDDEN * 2);
    unsigned short* w1l = (unsigned short*)alloc((size_t)HIDDEN * HIDDEN * 2);
    unsigned short* w2h = (unsigned short*)alloc((size_t)HIDDEN * HIDDEN * 2);
    unsigned short* w2l = (unsigned short*)alloc((size_t)HIDDEN * HIDDEN * 2);
    (void)ws_size; (void)in_sizes; (void)n_in; (void)out_size;

    hipMemsetAsync(deg,     0, (size_t)N_NODES * 4, stream);
    hipMemsetAsync(counter, 0, 256, stream);

    // CSR build: ONE atomic pass + scan + atomic-free place
    count_pos_kernel<<<(N_EDGES + 255) / 256, 256, 0, stream>>>(dst, deg, epos);
    offsets_kernel<<<(N_NODES + 255) / 256, 256, 0, stream>>>(deg, rowst, counter);
    place_kernel<<<(N_EDGES + 255) / 256, 256, 0, stream>>>(src, dst, epos, rowst, csr_src);

    // W split-transpose prep (once) + x -> bf16
    wsplit_kernel<<<(HIDDEN * HIDDEN + 255) / 256, 256, 0, stream>>>(W1, w1h, w1l);
    wsplit_kernel<<<(HIDDEN * HIDDEN + 255) / 256, 256, 0, stream>>>(W2, w2h, w2l);
    xconv_kernel<<<(N_NODES * HIDDEN / 8 + 255) / 256, 256, 0, stream>>>((const float4*)x, (uint4*)g_bf);

    const int agg_grid = (N_NODES * 16 + 255) / 256;
    const int mm_grid  = (N_NODES + 127) / 128;
    unsigned short* nul = (unsigned short*)nullptr;

    // layer 1
    agg_kernel<<<agg_grid, 256, 0, stream>>>((const uint4*)g_bf, rowst, deg, csr_src, (uint4*)th_buf, (uint4*)tl_buf);
    mm_mfma<<<mm_grid, 256, 0, stream>>>(th_buf, tl_buf, w1h, w1l, b1, (float*)nullptr, zh_buf, zl_buf, nul, 1);
    mm_mfma<<<mm_grid, 256, 0, stream>>>(zh_buf, zl_buf, w2h, w2l, b2, (float*)nullptr, nul, nul, g_bf, 1);
    // layer 2
    agg_kernel<<<agg_grid, 256, 0, stream>>>((const uint4*)g_bf, rowst, deg, csr_src, (uint4*)th_buf, (uint4*)tl_buf);
    mm_mfma<<<mm_grid, 256, 0, stream>>>(th_buf, tl_buf, w1h, w1l, b1, (float*)nullptr, zh_buf, zl_buf, nul, 1);
    mm_mfma<<<mm_grid, 256, 0, stream>>>(zh_buf, zl_buf, w2h, w2l, b2, (float*)nullptr, nul, nul, g_bf, 1);
    // layer 3 (no outer relu; fp32 h for pooling)
    agg_kernel<<<agg_grid, 256, 0, stream>>>((const uint4*)g_bf, rowst, deg, csr_src, (uint4*)th_buf, (uint4*)tl_buf);
    mm_mfma<<<mm_grid, 256, 0, stream>>>(th_buf, tl_buf, w1h, w1l, b1, (float*)nullptr, zh_buf, zl_buf, nul, 1);
    mm_mfma<<<mm_grid, 256, 0, stream>>>(zh_buf, zl_buf, w2h, w2l, b2, h_buf, nul, nul, nul, 0);

    // fused mean-pool + head
    pool_head_kernel<<<N_GRAPHS, 256, 0, stream>>>(h_buf, bat, Wl, bl, out);
}

// Round 6
// 381.948 us; speedup vs baseline: 1.9973x; 1.0581x over previous
//
#include <hip/hip_runtime.h>

#define N_NODES  50000
#define N_EDGES  800000
#define HIDDEN   128
#define N_GRAPHS 256
#define N_CLASSES 10
#define WLD 136   // padded LDS leading dim for W tiles (bank shift 4/row -> 2-way max, free)

typedef short short8 __attribute__((ext_vector_type(8)));
typedef float floatx4 __attribute__((ext_vector_type(4)));

__device__ inline unsigned short bf16_rtne(float x) {
    unsigned u = __float_as_uint(x);
    unsigned r = ((u >> 16) & 1u) + 0x7fffu;
    return (unsigned short)((u + r) >> 16);
}

// split fp32 into bf16 hi (truncate) + bf16 lo (truncated residual)
__device__ inline void bf16_split(float a, unsigned short& hi, unsigned short& lo) {
    unsigned u = __float_as_uint(a);
    hi = (unsigned short)(u >> 16);
    float res = a - __uint_as_float(u & 0xffff0000u);
    lo = (unsigned short)(__float_as_uint(res) >> 16);
}

// ---------------- CSR build: ONE atomic pass ----------------
__global__ void count_pos_kernel(const int* __restrict__ dst, int* __restrict__ deg,
                                 int* __restrict__ epos) {
    int e = blockIdx.x * blockDim.x + threadIdx.x;
    if (e < N_EDGES) epos[e] = atomicAdd(&deg[dst[e]], 1);
}

__global__ void offsets_kernel(const int* __restrict__ deg, int* __restrict__ row_start,
                               int* __restrict__ counter) {
    int n = blockIdx.x * blockDim.x + threadIdx.x;
    int d = (n < N_NODES) ? deg[n] : 0;
    int lane = threadIdx.x & 63;
    int incl = d;
    #pragma unroll
    for (int off = 1; off < 64; off <<= 1) {
        int v = __shfl_up(incl, off, 64);
        if (lane >= off) incl += v;
    }
    int excl = incl - d;
    int total = __shfl(incl, 63, 64);
    int base = 0;
    if (lane == 0) base = atomicAdd(counter, total);
    base = __shfl(base, 0, 64);
    if (n < N_NODES) row_start[n] = base + excl;
}

// atomic-free scatter
__global__ void place_kernel(const int* __restrict__ src, const int* __restrict__ dst,
                             const int* __restrict__ epos, const int* __restrict__ row_start,
                             int* __restrict__ csr_src) {
    int e = blockIdx.x * blockDim.x + threadIdx.x;
    if (e >= N_EDGES) return;
    csr_src[row_start[dst[e]] + epos[e]] = src[e];
}

// ---------------- x -> bf16 convert (once) ----------------
__global__ void xconv_kernel(const float4* __restrict__ X, uint4* __restrict__ Xb) {
    int i = blockIdx.x * blockDim.x + threadIdx.x;   // over uint4 = 8 bf16
    if (i >= N_NODES * HIDDEN / 8) return;
    float4 a = X[2 * i], b = X[2 * i + 1];
    uint4 o;
    o.x = (unsigned)bf16_rtne(a.x) | ((unsigned)bf16_rtne(a.y) << 16);
    o.y = (unsigned)bf16_rtne(a.z) | ((unsigned)bf16_rtne(a.w) << 16);
    o.z = (unsigned)bf16_rtne(b.x) | ((unsigned)bf16_rtne(b.y) << 16);
    o.w = (unsigned)bf16_rtne(b.z) | ((unsigned)bf16_rtne(b.w) << 16);
    Xb[i] = o;
}

// ---------------- aggregation (bf16 gather): T = rtne_bf16( Xb[n] + sum Xb[src] ) ----------------
__device__ inline void acc_bf2(unsigned d, float& f0, float& f1) {
    f0 += __uint_as_float(d << 16);
    f1 += __uint_as_float(d & 0xffff0000u);
}

__global__ void agg_kernel(const uint4* __restrict__ Xb, const int* __restrict__ row_start,
                           const int* __restrict__ deg, const int* __restrict__ csr_src,
                           uint4* __restrict__ Tb) {
    int gid = blockIdx.x * blockDim.x + threadIdx.x;
    int n = gid >> 4;
    int c = gid & 15;
    if (n >= N_NODES) return;
    float a[8];
    #pragma unroll
    for (int j = 0; j < 8; ++j) a[j] = 0.f;
    {   // self term
        uint4 v = Xb[(size_t)n * 16 + c];
        acc_bf2(v.x, a[0], a[1]); acc_bf2(v.y, a[2], a[3]);
        acc_bf2(v.z, a[4], a[5]); acc_bf2(v.w, a[6], a[7]);
    }
    int rs = row_start[n];
    int d  = deg[n];
    int i = 0;
    for (; i + 4 <= d; i += 4) {
        int s0 = csr_src[rs + i + 0];
        int s1 = csr_src[rs + i + 1];
        int s2 = csr_src[rs + i + 2];
        int s3 = csr_src[rs + i + 3];
        uint4 v0 = Xb[(size_t)s0 * 16 + c];
        uint4 v1 = Xb[(size_t)s1 * 16 + c];
        uint4 v2 = Xb[(size_t)s2 * 16 + c];
        uint4 v3 = Xb[(size_t)s3 * 16 + c];
        acc_bf2(v0.x, a[0], a[1]); acc_bf2(v0.y, a[2], a[3]); acc_bf2(v0.z, a[4], a[5]); acc_bf2(v0.w, a[6], a[7]);
        acc_bf2(v1.x, a[0], a[1]); acc_bf2(v1.y, a[2], a[3]); acc_bf2(v1.z, a[4], a[5]); acc_bf2(v1.w, a[6], a[7]);
        acc_bf2(v2.x, a[0], a[1]); acc_bf2(v2.y, a[2], a[3]); acc_bf2(v2.z, a[4], a[5]); acc_bf2(v2.w, a[6], a[7]);
        acc_bf2(v3.x, a[0], a[1]); acc_bf2(v3.y, a[2], a[3]); acc_bf2(v3.z, a[4], a[5]); acc_bf2(v3.w, a[6], a[7]);
    }
    for (; i < d; ++i) {
        int s = csr_src[rs + i];
        uint4 v = Xb[(size_t)s * 16 + c];
        acc_bf2(v.x, a[0], a[1]); acc_bf2(v.y, a[2], a[3]);
        acc_bf2(v.z, a[4], a[5]); acc_bf2(v.w, a[6], a[7]);
    }
    uint4 o;
    o.x = (unsigned)bf16_rtne(a[0]) | ((unsigned)bf16_rtne(a[1]) << 16);
    o.y = (unsigned)bf16_rtne(a[2]) | ((unsigned)bf16_rtne(a[3]) << 16);
    o.z = (unsigned)bf16_rtne(a[4]) | ((unsigned)bf16_rtne(a[5]) << 16);
    o.w = (unsigned)bf16_rtne(a[6]) | ((unsigned)bf16_rtne(a[7]) << 16);
    Tb[(size_t)n * 16 + c] = o;
}

// ---------------- W prep: split fp32 W[k][n] into transposed bf16 hi/lo Wt[n][k] ----------------
__global__ void wsplit_kernel(const float* __restrict__ W, unsigned short* __restrict__ Wh,
                              unsigned short* __restrict__ Wl) {
    int idx = blockIdx.x * blockDim.x + threadIdx.x;   // 16384
    if (idx >= HIDDEN * HIDDEN) return;
    int k = idx >> 7, n = idx & 127;
    unsigned short hi, lo;
    bf16_split(W[idx], hi, lo);
    Wh[n * HIDDEN + k] = hi;
    Wl[n * HIDDEN + k] = lo;
}

// ---------------- MFMA matmul: out = act(A @ W + b) ----------------
// A: single bf16 row-major. W hi/lo staged in LDS (padded).
// A@W = A@Wh + A@Wl (W split exact; activation rounding is the accepted error site).
// Outputs: C fp32 (if non-null) and/or Cb rtne bf16 (if non-null).
__global__ __launch_bounds__(256)
void mm_mfma(const unsigned short* __restrict__ Ab,
             const unsigned short* __restrict__ Bh, const unsigned short* __restrict__ Bl,
             const float* __restrict__ bias,
             float* __restrict__ C, unsigned short* __restrict__ Cb, int relu) {
    __shared__ unsigned short WhS[HIDDEN * WLD];   // 34.8 KB
    __shared__ unsigned short WlS[HIDDEN * WLD];   // 34.8 KB

    int t = threadIdx.x;
    {   // stage W hi/lo: 2048 ushort8 each, 8 per thread, coalesced global reads
        const short8* gh = (const short8*)Bh;
        const short8* gl = (const short8*)Bl;
        #pragma unroll
        for (int i = 0; i < 8; ++i) {
            int idx = i * 256 + t;              // ushort8 index 0..2047
            int row = idx >> 4, kk = (idx & 15) * 8;
            *(short8*)(WhS + row * WLD + kk) = gh[idx];
            *(short8*)(WlS + row * WLD + kk) = gl[idx];
        }
    }
    __syncthreads();

    int w = t >> 6;
    int l = t & 63;
    int lane16 = l & 15;
    int quad = l >> 4;
    int row_base = blockIdx.x * 128 + w * 32;

    floatx4 acc[2][8];
    #pragma unroll
    for (int m = 0; m < 2; ++m)
        #pragma unroll
        for (int nt = 0; nt < 8; ++nt) acc[m][nt] = (floatx4){0.f, 0.f, 0.f, 0.f};

    #pragma unroll
    for (int kc = 0; kc < 4; ++kc) {
        int k0 = kc * 32 + quad * 8;
        short8 af[2];
        #pragma unroll
        for (int m = 0; m < 2; ++m) {
            int r = row_base + m * 16 + lane16;
            if (r < N_NODES) af[m] = *(const short8*)(Ab + (size_t)r * HIDDEN + k0);
            else             af[m] = (short8){0,0,0,0,0,0,0,0};
        }
        short8 bh[8], bl8[8];
        #pragma unroll
        for (int nt = 0; nt < 8; ++nt) {
            bh[nt]  = *(const short8*)(WhS + (nt * 16 + lane16) * WLD + k0);
            bl8[nt] = *(const short8*)(WlS + (nt * 16 + lane16) * WLD + k0);
        }
        #pragma unroll
        for (int m = 0; m < 2; ++m)
            #pragma unroll
            for (int nt = 0; nt < 8; ++nt) {
                acc[m][nt] = __builtin_amdgcn_mfma_f32_16x16x32_bf16(af[m], bh[nt],  acc[m][nt], 0, 0, 0);
                acc[m][nt] = __builtin_amdgcn_mfma_f32_16x16x32_bf16(af[m], bl8[nt], acc[m][nt], 0, 0, 0);
            }
    }
    // epilogue: C/D layout col=lane&15, row=quad*4+reg
    #pragma unroll
    for (int nt = 0; nt < 8; ++nt) {
        int col = nt * 16 + lane16;
        float b = bias[col];
        #pragma unroll
        for (int m = 0; m < 2; ++m) {
            #pragma unroll
            for (int reg = 0; reg < 4; ++reg) {
                int r = row_base + m * 16 + quad * 4 + reg;
                if (r < N_NODES) {
                    float o = acc[m][nt][reg] + b;
                    if (relu) o = fmaxf(o, 0.f);
                    size_t oi = (size_t)r * HIDDEN + col;
                    if (C)  C[oi]  = o;
                    if (Cb) Cb[oi] = bf16_rtne(o);
                }
            }
        }
    }
}

// ---------------- fused pool + mean + linear head ----------------
__global__ void pool_head_kernel(const float* __restrict__ H, const int* __restrict__ batch,
                                 const float* __restrict__ Wl, const float* __restrict__ bl,
                                 float* __restrict__ out) {
    int g = blockIdx.x;
    int t = threadIdx.x;   // 256 threads
    __shared__ int bounds[2];
    __shared__ float acc2[2 * HIDDEN];
    __shared__ float mean[HIDDEN];

    if (t < 2) {
        int target = g + t;
        int lo = 0, hi = N_NODES;
        while (lo < hi) {
            int mid = (lo + hi) >> 1;
            if (batch[mid] < target) lo = mid + 1; else hi = mid;
        }
        bounds[t] = lo;
    }
    __syncthreads();
    int r0 = bounds[0], r1 = bounds[1];

    int c = t & 127, half = t >> 7;
    float s = 0.f;
    for (int r = r0 + half; r < r1; r += 2)
        s += H[(size_t)r * HIDDEN + c];
    acc2[half * HIDDEN + c] = s;
    __syncthreads();
    if (t < HIDDEN) {
        float cntf = (float)(r1 - r0);
        mean[t] = (acc2[t] + acc2[HIDDEN + t]) / fmaxf(cntf, 1.0f);
    }
    __syncthreads();
    if (t < N_CLASSES) {
        float o = bl[t];
        #pragma unroll 8
        for (int k = 0; k < HIDDEN; ++k) o = fmaf(mean[k], Wl[k * N_CLASSES + t], o);
        out[(size_t)g * N_CLASSES + t] = o;
    }
}

extern "C" void kernel_launch(void* const* d_in, const int* in_sizes, int n_in,
                              void* d_out, int out_size, void* d_ws, size_t ws_size,
                              hipStream_t stream) {
    const float* x   = (const float*)d_in[0];
    const int*   ei  = (const int*)d_in[1];       // [2][N_EDGES]: row0=src, row1=dst
    const int*   bat = (const int*)d_in[2];
    const float* W1  = (const float*)d_in[3];
    const float* b1  = (const float*)d_in[4];
    const float* W2  = (const float*)d_in[5];
    const float* b2  = (const float*)d_in[6];
    const float* Wl  = (const float*)d_in[7];
    const float* bl  = (const float*)d_in[8];
    float* out = (float*)d_out;

    const int* src = ei;
    const int* dst = ei + N_EDGES;

    char* w = (char*)d_ws;
    size_t off = 0;
    auto alloc = [&](size_t bytes) { void* p = w + off; off = (off + bytes + 255) & ~(size_t)255; return p; };
    unsigned short* g_bf  = (unsigned short*)alloc((size_t)N_NODES * HIDDEN * 2);  // gather table (bf16)
    unsigned short* t_bf  = (unsigned short*)alloc((size_t)N_NODES * HIDDEN * 2);  // agg out (bf16)
    unsigned short* z_bf  = (unsigned short*)alloc((size_t)N_NODES * HIDDEN * 2);  // mm1 out (bf16)
    float* h_buf   = (float*)alloc((size_t)N_NODES * HIDDEN * 4);                  // layer-3 out (fp32)
    int*   deg     = (int*)  alloc((size_t)N_NODES * 4);
    int*   rowst   = (int*)  alloc((size_t)N_NODES * 4);
    int*   epos    = (int*)  alloc((size_t)N_EDGES * 4);
    int*   csr_src = (int*)  alloc((size_t)N_EDGES * 4);
    int*   counter = (int*)  alloc(256);
    unsigned short* w1h = (unsigned short*)alloc((size_t)HIDDEN * HIDDEN * 2);
    unsigned short* w1l = (unsigned short*)alloc((size_t)HIDDEN * HIDDEN * 2);
    unsigned short* w2h = (unsigned short*)alloc((size_t)HIDDEN * HIDDEN * 2);
    unsigned short* w2l = (unsigned short*)alloc((size_t)HIDDEN * HIDDEN * 2);
    (void)ws_size; (void)in_sizes; (void)n_in; (void)out_size;

    hipMemsetAsync(deg,     0, (size_t)N_NODES * 4, stream);
    hipMemsetAsync(counter, 0, 256, stream);

    // CSR build: ONE atomic pass + scan + atomic-free place
    count_pos_kernel<<<(N_EDGES + 255) / 256, 256, 0, stream>>>(dst, deg, epos);
    offsets_kernel<<<(N_NODES + 255) / 256, 256, 0, stream>>>(deg, rowst, counter);
    place_kernel<<<(N_EDGES + 255) / 256, 256, 0, stream>>>(src, dst, epos, rowst, csr_src);

    // W split-transpose prep (once) + x -> bf16
    wsplit_kernel<<<(HIDDEN * HIDDEN + 255) / 256, 256, 0, stream>>>(W1, w1h, w1l);
    wsplit_kernel<<<(HIDDEN * HIDDEN + 255) / 256, 256, 0, stream>>>(W2, w2h, w2l);
    xconv_kernel<<<(N_NODES * HIDDEN / 8 + 255) / 256, 256, 0, stream>>>((const float4*)x, (uint4*)g_bf);

    const int agg_grid = (N_NODES * 16 + 255) / 256;
    const int mm_grid  = (N_NODES + 127) / 128;
    unsigned short* nul = (unsigned short*)nullptr;

    // layer 1
    agg_kernel<<<agg_grid, 256, 0, stream>>>((const uint4*)g_bf, rowst, deg, csr_src, (uint4*)t_bf);
    mm_mfma<<<mm_grid, 256, 0, stream>>>(t_bf, w1h, w1l, b1, (float*)nullptr, z_bf, 1);
    mm_mfma<<<mm_grid, 256, 0, stream>>>(z_bf, w2h, w2l, b2, (float*)nullptr, g_bf, 1);
    // layer 2
    agg_kernel<<<agg_grid, 256, 0, stream>>>((const uint4*)g_bf, rowst, deg, csr_src, (uint4*)t_bf);
    mm_mfma<<<mm_grid, 256, 0, stream>>>(t_bf, w1h, w1l, b1, (float*)nullptr, z_bf, 1);
    mm_mfma<<<mm_grid, 256, 0, stream>>>(z_bf, w2h, w2l, b2, (float*)nullptr, g_bf, 1);
    // layer 3 (no outer relu; fp32 h for pooling)
    agg_kernel<<<agg_grid, 256, 0, stream>>>((const uint4*)g_bf, rowst, deg, csr_src, (uint4*)t_bf);
    mm_mfma<<<mm_grid, 256, 0, stream>>>(t_bf, w1h, w1l, b1, (float*)nullptr, z_bf, 1);
    mm_mfma<<<mm_grid, 256, 0, stream>>>(z_bf, w2h, w2l, b2, h_buf, nul, 0);

    // fused mean-pool + head
    pool_head_kernel<<<N_GRAPHS, 256, 0, stream>>>(h_buf, bat, Wl, bl, out);
}